// Round 2
// baseline (89.823 us; speedup 1.0000x reference)
//
#include <hip/hip_runtime.h>

#define Bn 8
#define Nn 2048
#define Dn 128
#define OUTn 128

typedef __attribute__((ext_vector_type(8))) short bf16x8;     // MFMA A/B operand (8 bf16)
typedef __attribute__((ext_vector_type(8))) unsigned short ushort8;
typedef __attribute__((ext_vector_type(4))) float f32x4;      // MFMA C/D
typedef __attribute__((ext_vector_type(4))) int int4v;
typedef __attribute__((ext_vector_type(4))) float float4v;

__device__ __forceinline__ unsigned short f2bf(float f) {
  unsigned int u = __builtin_bit_cast(unsigned int, f);
  u += 0x7FFFu + ((u >> 16) & 1u);   // round-to-nearest-even
  return (unsigned short)(u >> 16);
}

// ---------------- prep 1: input [b][n][d] fp32 -> inputT [b][d][n] bf16 ----------------
__global__ __launch_bounds__(256) void gcn_transpose_in(const float* __restrict__ in,
                                                        unsigned short* __restrict__ inT) {
  const int b = blockIdx.x >> 5;
  const int n0 = (blockIdx.x & 31) * 64;
  __shared__ __attribute__((aligned(16))) unsigned short lds[64][130];
  const int tid = threadIdx.x;
  #pragma unroll
  for (int c = 0; c < 32; ++c) {
    int e = tid + c * 256;            // 0..8191
    int i = e >> 7, d = e & 127;
    lds[i][d] = f2bf(in[((size_t)(b * Nn + n0 + i)) * Dn + d]);
  }
  __syncthreads();
  #pragma unroll
  for (int c = 0; c < 4; ++c) {
    int ch = tid + c * 256;           // 0..1023
    int d = ch >> 3, g = (ch & 7) * 8;
    ushort8 v;
    #pragma unroll
    for (int e = 0; e < 8; ++e) v[e] = lds[g + e][d];
    *(ushort8*)(inT + ((size_t)(b * Dn + d)) * Nn + n0 + g) = v;
  }
}

// ---------------- prep 2: W [2D][OUT] fp32 -> WT [OUT][2D] bf16 ----------------
__global__ __launch_bounds__(256) void gcn_prep_wt(const float* __restrict__ W,
                                                   unsigned short* __restrict__ WT) {
  int gid = blockIdx.x * 256 + threadIdx.x;      // 0..32767
  int j = gid >> 8, k = gid & 255;               // WT[j][k] = W[k][j]
  WT[gid] = f2bf(W[k * OUTn + j]);
}

// ---------------- main fused kernel ----------------
// 1024 blocks of 256 threads (4 waves); block handles 16 rows of one batch.
// GEMM1: A = adj tile (LDS, double-buffered, int->bf16 on the fly),
//        B = inT read DIRECT from global (L2-hot; 64B-contiguous per d-row).
// GEMM2: A = [x (direct from input_, cvt) | agg (LDS)], B = WT direct.
__global__ __launch_bounds__(256, 4) void gcn_main(
    const float* __restrict__ input_, const int* __restrict__ adj,
    const float* __restrict__ bvec, const unsigned short* __restrict__ inT,
    const unsigned short* __restrict__ WT, float* __restrict__ out) {
  constexpr int BM = 16, KB = 128, PAD = 8, NT = Nn / KB;
  __shared__ __attribute__((aligned(16))) unsigned short As[2][BM][KB + PAD]; // 8.7 KB
  __shared__ __attribute__((aligned(16))) unsigned short aggl[BM][Dn + PAD];  // 4.4 KB
  __shared__ float degs[BM];
  __shared__ float rowsum[BM][4];

  const int tid = threadIdx.x;
  const int w = tid >> 6;          // wave 0..3 -> output cols w*32..w*32+31
  const int l = tid & 63;
  const int lr = l & 15, lg = l >> 4;

  // bijective XCD swizzle: nwg=1024, 8 XCDs -> XCD x gets contiguous chunk = one batch
  const int wg = (blockIdx.x & 7) * 128 + (blockIdx.x >> 3);
  const int bb = wg >> 7;
  const int row0 = (wg & 127) * BM;

  // A staging: thread owns row ar, 8 consecutive ints at col base ac per K-tile
  const int ar = tid >> 4;          // 0..15
  const int ac = (tid & 15) * 8;    // 0..120
  const int* adj_row = adj + ((size_t)(bb * Nn + row0 + ar)) * Nn + ac;
  const unsigned short* inTb = inT + (size_t)bb * Dn * Nn;

  f32x4 acc[2] = {};
  int dsum = 0;
  int4v abuf[2][2];

  // prologue: tile 0 load+convert, tile 1 load in flight
  abuf[0][0] = *(const int4v*)(adj_row);
  abuf[0][1] = *(const int4v*)(adj_row + 4);
  {
    ushort8 awv;
    #pragma unroll
    for (int c = 0; c < 2; ++c)
      #pragma unroll
      for (int e = 0; e < 4; ++e) {
        int v = abuf[0][c][e];
        dsum += (v != 0);
        awv[c * 4 + e] = (v != 0) ? (unsigned short)0x3F80u : (unsigned short)0u;
      }
    *(ushort8*)&As[0][ar][ac] = awv;
  }
  abuf[1][0] = *(const int4v*)(adj_row + KB);
  abuf[1][1] = *(const int4v*)(adj_row + KB + 4);
  __syncthreads();

  for (int kt = 0; kt < NT; ++kt) {
    const int cur = kt & 1;
    // A frags from LDS, B frags direct from global (L2), 8 MFMA
    bf16x8 af[4];
    #pragma unroll
    for (int kc = 0; kc < 4; ++kc)
      af[kc] = *(const bf16x8*)&As[cur][lr][kc * 32 + lg * 8];
    #pragma unroll
    for (int kc = 0; kc < 4; ++kc)
      #pragma unroll
      for (int cf = 0; cf < 2; ++cf) {
        bf16x8 bfm = *(const bf16x8*)(inTb + (size_t)(w * 32 + cf * 16 + lr) * Nn +
                                      kt * KB + kc * 32 + lg * 8);
        acc[cf] = __builtin_amdgcn_mfma_f32_16x16x32_bf16(af[kc], bfm, acc[cf], 0, 0, 0);
      }
    if (kt < NT - 1) {
      // convert tile kt+1 (already in regs) -> As[cur^1]; accumulate degree
      const int p = (kt + 1) & 1;
      ushort8 awv;
      #pragma unroll
      for (int c = 0; c < 2; ++c)
        #pragma unroll
        for (int e = 0; e < 4; ++e) {
          int v = abuf[p][c][e];
          dsum += (v != 0);
          awv[c * 4 + e] = (v != 0) ? (unsigned short)0x3F80u : (unsigned short)0u;
        }
      *(ushort8*)&As[cur ^ 1][ar][ac] = awv;
      // issue tile kt+2 loads (2-deep in flight across the barrier)
      if (kt < NT - 2) {
        const int k0 = (kt + 2) * KB;
        abuf[kt & 1][0] = *(const int4v*)(adj_row + k0);
        abuf[kt & 1][1] = *(const int4v*)(adj_row + k0 + 4);
      }
      __syncthreads();
    }
  }

  // ---- degree: reduce across the 16 staging threads of each row ----
  {
    int s = dsum;
    s += __shfl_down(s, 8);
    s += __shfl_down(s, 4);
    s += __shfl_down(s, 2);
    s += __shfl_down(s, 1);
    if ((tid & 15) == 0) {
      float fd = (float)s;
      degs[tid >> 4] = (fd == 0.0f) ? 1.0f : fd;
    }
  }
  __syncthreads();

  // ---- stage agg (bf16, /deg) in LDS for GEMM2 A-frag redistribution ----
  #pragma unroll
  for (int cf = 0; cf < 2; ++cf)
    #pragma unroll
    for (int reg = 0; reg < 4; ++reg) {
      int row = lg * 4 + reg;
      aggl[row][w * 32 + cf * 16 + lr] = f2bf(acc[cf][reg] / degs[row]);
    }
  __syncthreads();

  // ---- GEMM2: out_pre = [x | agg] @ W  (K=256); x direct from input_, B from WT ----
  f32x4 acc2[2] = {};
  const float* xrow = input_ + ((size_t)(bb * Nn + row0 + lr)) * Dn;
  #pragma unroll
  for (int ks = 0; ks < 8; ++ks) {
    bf16x8 af;
    if (ks < 4) {
      float4v f0 = *(const float4v*)(xrow + ks * 32 + lg * 8);
      float4v f1 = *(const float4v*)(xrow + ks * 32 + lg * 8 + 4);
      ushort8 v;
      #pragma unroll
      for (int e = 0; e < 4; ++e) { v[e] = f2bf(f0[e]); v[e + 4] = f2bf(f1[e]); }
      af = __builtin_bit_cast(bf16x8, v);
    } else {
      af = *(const bf16x8*)&aggl[lr][(ks - 4) * 32 + lg * 8];
    }
    #pragma unroll
    for (int cf = 0; cf < 2; ++cf) {
      bf16x8 bw = *(const bf16x8*)(WT + (size_t)(w * 32 + cf * 16 + lr) * 256 +
                                   ks * 32 + lg * 8);
      acc2[cf] = __builtin_amdgcn_mfma_f32_16x16x32_bf16(af, bw, acc2[cf], 0, 0, 0);
    }
  }

  // ---- bias + sigmoid + row L2-norm + store ----
  float bcol[2];
  bcol[0] = bvec[w * 32 + lr];
  bcol[1] = bvec[w * 32 + 16 + lr];
  float sg[2][4];
  #pragma unroll
  for (int cf = 0; cf < 2; ++cf)
    #pragma unroll
    for (int reg = 0; reg < 4; ++reg) {
      float x = acc2[cf][reg] + bcol[cf];
      sg[cf][reg] = 1.0f / (1.0f + expf(-x));
    }
  #pragma unroll
  for (int reg = 0; reg < 4; ++reg) {
    float p = sg[0][reg] * sg[0][reg] + sg[1][reg] * sg[1][reg];
    p += __shfl_xor(p, 1);
    p += __shfl_xor(p, 2);
    p += __shfl_xor(p, 4);
    p += __shfl_xor(p, 8);
    if (lr == 0) rowsum[lg * 4 + reg][w] = p;
  }
  __syncthreads();
  #pragma unroll
  for (int reg = 0; reg < 4; ++reg) {
    int row = lg * 4 + reg;
    float inv = rsqrtf(rowsum[row][0] + rowsum[row][1] + rowsum[row][2] + rowsum[row][3]);
    #pragma unroll
    for (int cf = 0; cf < 2; ++cf)
      out[((size_t)(bb * Nn + row0 + row)) * OUTn + w * 32 + cf * 16 + lr] =
          sg[cf][reg] * inv;
  }
}

extern "C" void kernel_launch(void* const* d_in, const int* in_sizes, int n_in,
                              void* d_out, int out_size, void* d_ws, size_t ws_size,
                              hipStream_t stream) {
  (void)in_sizes; (void)n_in; (void)out_size; (void)ws_size;
  const float* input_ = (const float*)d_in[0];
  const int* adj = (const int*)d_in[1];
  const float* W = (const float*)d_in[2];
  const float* bvec = (const float*)d_in[3];
  float* out = (float*)d_out;

  unsigned short* inT = (unsigned short*)d_ws;                 // 8*128*2048 bf16 = 4 MB
  unsigned short* WT = inT + (size_t)Bn * Dn * Nn;             // 128*256 bf16 = 64 KB

  hipLaunchKernelGGL(gcn_transpose_in, dim3(256), dim3(256), 0, stream, input_, inT);
  hipLaunchKernelGGL(gcn_prep_wt, dim3(128), dim3(256), 0, stream, W, WT);
  hipLaunchKernelGGL(gcn_main, dim3(1024), dim3(256), 0, stream, input_, adj, bvec, inT, WT, out);
}

// Round 4
// 52.716 us; speedup vs baseline: 1.7039x; 1.7039x over previous
//
#include <hip/hip_runtime.h>

#define Bn 8
#define Nn 2048
#define Dn 128
#define OUTn 128

typedef __attribute__((ext_vector_type(8))) short bf16x8;     // MFMA A/B operand (8 bf16)
typedef __attribute__((ext_vector_type(8))) unsigned short ushort8;
typedef __attribute__((ext_vector_type(4))) float f32x4;      // MFMA C/D
typedef __attribute__((ext_vector_type(4))) int int4v;
typedef __attribute__((ext_vector_type(4))) float float4v;

__device__ __forceinline__ unsigned short f2bf(float f) {
  unsigned int u = __builtin_bit_cast(unsigned int, f);
  u += 0x7FFFu + ((u >> 16) & 1u);   // round-to-nearest-even
  return (unsigned short)(u >> 16);
}

// ---------------- merged prep: transpose input + transpose W ----------------
// blocks 0..255: input [b][n][d] fp32 -> inT [b][d][n] bf16
// blocks 256..383: W [2D][OUT] fp32 -> WT [OUT][2D] bf16
__global__ __launch_bounds__(256) void gcn_prep(const float* __restrict__ in,
                                                const float* __restrict__ W,
                                                unsigned short* __restrict__ inT,
                                                unsigned short* __restrict__ WT) {
  const int tid = threadIdx.x;
  if (blockIdx.x >= 256) {
    int gid = (blockIdx.x - 256) * 256 + tid;    // 0..32767
    int j = gid >> 8, k = gid & 255;             // WT[j][k] = W[k][j]
    WT[gid] = f2bf(W[k * OUTn + j]);
    return;
  }
  const int b = blockIdx.x >> 5;
  const int n0 = (blockIdx.x & 31) * 64;
  __shared__ __attribute__((aligned(16))) unsigned short lds[64][130];
  #pragma unroll
  for (int c = 0; c < 32; ++c) {
    int e = tid + c * 256;            // 0..8191
    int i = e >> 7, d = e & 127;
    lds[i][d] = f2bf(in[((size_t)(b * Nn + n0 + i)) * Dn + d]);
  }
  __syncthreads();
  #pragma unroll
  for (int c = 0; c < 4; ++c) {
    int ch = tid + c * 256;           // 0..1023
    int d = ch >> 3, g = (ch & 7) * 8;
    ushort8 v;
    #pragma unroll
    for (int e = 0; e < 8; ++e) v[e] = lds[g + e][d];
    *(ushort8*)(inT + ((size_t)(b * Dn + d)) * Nn + n0 + g) = v;
  }
}

// ---------------- main fused kernel ----------------
// 1024 blocks x 256 threads (4 waves); block = 16 rows of one batch.
// GEMM1: A = adj tile 16x64 (int->bf16, LDS), B = inT tile 128x64 (LDS),
// both reg-prefetched 1 tile ahead. ~26KB LDS -> 4 blocks/CU resident.
__global__ __launch_bounds__(256, 4) void gcn_main(
    const float* __restrict__ input_, const int* __restrict__ adj,
    const float* __restrict__ bvec, const unsigned short* __restrict__ inT,
    const unsigned short* __restrict__ WT, float* __restrict__ out) {
  constexpr int BM = 16, KB = 64, PAD = 8, NT = Nn / KB;
  __shared__ __attribute__((aligned(16))) unsigned short As[BM][KB + PAD];   // 2.3 KB
  __shared__ __attribute__((aligned(16))) unsigned short Bs[Dn][KB + PAD];   // 18.4 KB
  __shared__ __attribute__((aligned(16))) unsigned short aggl[BM][Dn + PAD]; // 4.4 KB
  __shared__ float degs[BM];
  __shared__ float rowsum[BM][4];

  const int tid = threadIdx.x;
  const int w = tid >> 6;          // wave 0..3 -> output cols w*32..w*32+31
  const int l = tid & 63;
  const int lr = l & 15, lg = l >> 4;

  // bijective XCD swizzle: nwg=1024 (%8==0) -> each XCD gets one batch
  const int wg = (blockIdx.x & 7) * 128 + (blockIdx.x >> 3);
  const int bb = wg >> 7;
  const int row0 = (wg & 127) * BM;

  // A staging: thread owns row ar, 4 consecutive ints at col ac per K-tile
  const int ar = tid >> 4;          // 0..15
  const int ac = (tid & 15) * 4;    // 0..60
  const int* adj_row = adj + ((size_t)(bb * Nn + row0 + ar)) * Nn + ac;
  const unsigned short* inTb = inT + (size_t)bb * Dn * Nn;
  // B staging: 4 chunks of ushort8; chunk c: d = (tid+c*256)>>3, off = ((tid+c*256)&7)*8
  const int bd0 = tid >> 3;          // d for chunk 0; chunk c adds 32
  const int boff = (tid & 7) * 8;

  f32x4 acc[2] = {};
  int dsum = 0;
  int4v a_reg;
  ushort8 b_reg[4];

  // prologue: tile 0 into regs
  a_reg = *(const int4v*)(adj_row);
  #pragma unroll
  for (int c = 0; c < 4; ++c)
    b_reg[c] = *(const ushort8*)(inTb + (size_t)(bd0 + c * 32) * Nn + boff);

  for (int kt = 0; kt < NT; ++kt) {
    if (kt) __syncthreads();               // all waves done reading tile kt-1
    // convert + write A tile (accumulate degree), write B tile
    {
      unsigned long long aw = 0;
      #pragma unroll
      for (int e = 0; e < 4; ++e) {
        int v = a_reg[e];
        dsum += (v != 0);
        if (v != 0) aw |= (0x3F80ull << (16 * e));
      }
      *(unsigned long long*)&As[ar][ac] = aw;
    }
    #pragma unroll
    for (int c = 0; c < 4; ++c)
      *(ushort8*)&Bs[bd0 + c * 32][boff] = b_reg[c];
    __syncthreads();
    // prefetch tile kt+1 into regs (in flight during MFMA below)
    if (kt + 1 < NT) {
      const int k0 = (kt + 1) * KB;
      a_reg = *(const int4v*)(adj_row + k0);
      #pragma unroll
      for (int c = 0; c < 4; ++c)
        b_reg[c] = *(const ushort8*)(inTb + (size_t)(bd0 + c * 32) * Nn + k0 + boff);
    }
    // MFMA on tile kt: 4 per wave
    #pragma unroll
    for (int kc = 0; kc < 2; ++kc) {
      bf16x8 af = *(const bf16x8*)&As[lr][kc * 32 + lg * 8];
      #pragma unroll
      for (int cf = 0; cf < 2; ++cf) {
        bf16x8 bfm = *(const bf16x8*)&Bs[w * 32 + cf * 16 + lr][kc * 32 + lg * 8];
        acc[cf] = __builtin_amdgcn_mfma_f32_16x16x32_bf16(af, bfm, acc[cf], 0, 0, 0);
      }
    }
  }

  // ---- degree: reduce across the 16 staging threads of each row ----
  {
    int s = dsum;
    s += __shfl_down(s, 8);
    s += __shfl_down(s, 4);
    s += __shfl_down(s, 2);
    s += __shfl_down(s, 1);
    if ((tid & 15) == 0) {
      float fd = (float)s;
      degs[tid >> 4] = (fd == 0.0f) ? 1.0f : fd;
    }
  }
  __syncthreads();

  // ---- stage agg (bf16, /deg) in LDS for GEMM2 A-frag redistribution ----
  #pragma unroll
  for (int cf = 0; cf < 2; ++cf)
    #pragma unroll
    for (int reg = 0; reg < 4; ++reg) {
      int row = lg * 4 + reg;
      aggl[row][w * 32 + cf * 16 + lr] = f2bf(acc[cf][reg] / degs[row]);
    }
  __syncthreads();

  // ---- GEMM2: out_pre = [x | agg] @ W  (K=256); x direct from input_, B from WT ----
  f32x4 acc2[2] = {};
  const float* xrow = input_ + ((size_t)(bb * Nn + row0 + lr)) * Dn;
  #pragma unroll
  for (int ks = 0; ks < 8; ++ks) {
    bf16x8 af;
    if (ks < 4) {
      float4v f0 = *(const float4v*)(xrow + ks * 32 + lg * 8);
      float4v f1 = *(const float4v*)(xrow + ks * 32 + lg * 8 + 4);
      ushort8 v;
      #pragma unroll
      for (int e = 0; e < 4; ++e) { v[e] = f2bf(f0[e]); v[e + 4] = f2bf(f1[e]); }
      af = __builtin_bit_cast(bf16x8, v);
    } else {
      af = *(const bf16x8*)&aggl[lr][(ks - 4) * 32 + lg * 8];
    }
    #pragma unroll
    for (int cf = 0; cf < 2; ++cf) {
      bf16x8 bw = *(const bf16x8*)(WT + (size_t)(w * 32 + cf * 16 + lr) * 256 +
                                   ks * 32 + lg * 8);
      acc2[cf] = __builtin_amdgcn_mfma_f32_16x16x32_bf16(af, bw, acc2[cf], 0, 0, 0);
    }
  }

  // ---- bias + sigmoid + row L2-norm + store ----
  float bcol[2];
  bcol[0] = bvec[w * 32 + lr];
  bcol[1] = bvec[w * 32 + 16 + lr];
  float sg[2][4];
  #pragma unroll
  for (int cf = 0; cf < 2; ++cf)
    #pragma unroll
    for (int reg = 0; reg < 4; ++reg) {
      float x = acc2[cf][reg] + bcol[cf];
      sg[cf][reg] = 1.0f / (1.0f + expf(-x));
    }
  #pragma unroll
  for (int reg = 0; reg < 4; ++reg) {
    float p = sg[0][reg] * sg[0][reg] + sg[1][reg] * sg[1][reg];
    p += __shfl_xor(p, 1);
    p += __shfl_xor(p, 2);
    p += __shfl_xor(p, 4);
    p += __shfl_xor(p, 8);
    if (lr == 0) rowsum[lg * 4 + reg][w] = p;
  }
  __syncthreads();
  #pragma unroll
  for (int reg = 0; reg < 4; ++reg) {
    int row = lg * 4 + reg;
    float inv = rsqrtf(rowsum[row][0] + rowsum[row][1] + rowsum[row][2] + rowsum[row][3]);
    #pragma unroll
    for (int cf = 0; cf < 2; ++cf)
      out[((size_t)(bb * Nn + row0 + row)) * OUTn + w * 32 + cf * 16 + lr] =
          sg[cf][reg] * inv;
  }
}

extern "C" void kernel_launch(void* const* d_in, const int* in_sizes, int n_in,
                              void* d_out, int out_size, void* d_ws, size_t ws_size,
                              hipStream_t stream) {
  (void)in_sizes; (void)n_in; (void)out_size; (void)ws_size;
  const float* input_ = (const float*)d_in[0];
  const int* adj = (const int*)d_in[1];
  const float* W = (const float*)d_in[2];
  const float* bvec = (const float*)d_in[3];
  float* out = (float*)d_out;

  unsigned short* inT = (unsigned short*)d_ws;                 // 8*128*2048 bf16 = 4 MB
  unsigned short* WT = inT + (size_t)Bn * Dn * Nn;             // 128*256 bf16 = 64 KB

  hipLaunchKernelGGL(gcn_prep, dim3(384), dim3(256), 0, stream, input_, W, inT, WT);
  hipLaunchKernelGGL(gcn_main, dim3(1024), dim3(256), 0, stream, input_, adj, bvec, inT, WT, out);
}